// Round 14
// baseline (95.199 us; speedup 1.0000x reference)
//
#include <hip/hip_runtime.h>
#include <hip/hip_bf16.h>
#include <math.h>

#define D 64
#define NNODE 128

typedef __attribute__((ext_vector_type(8))) short short8;
typedef __attribute__((ext_vector_type(4))) float f32x4;

#define MFMA_B16(a,b,c) __builtin_amdgcn_mfma_f32_16x16x32_bf16((a),(b),(c),0,0,0)

// weight pack offsets (in shorts): layout [ntile][kfrag][lane(64)][jj(8)]
#define OFF_WR1   0        // 32x64  : KF=1, NT=4   -> 2048
#define OFF_WR2   2048     // 64x192 : KF=2, NT=12  -> 12288
#define OFF_L1M0  14336    // 64x64  : KF=2, NT=4   -> 4096
#define OFF_L1M1  18432    // 128x128: KF=4, NT=8   -> 16384
#define OFF_L2M0  34816
#define OFF_L2M1  38912
#define OFF_L2M2  55296
#define PACK_SHORTS 71680
#define PART_OFF  147456   // bytes; partials (f32) start here in d_ws

__device__ __forceinline__ unsigned short f2bf(float f) {
  unsigned int u = __float_as_uint(f);
  u += 0x7FFFu + ((u >> 16) & 1u);
  return (unsigned short)(u >> 16);
}
__device__ __forceinline__ float bf2f(unsigned short s) {
  return __uint_as_float(((unsigned int)s) << 16);
}

// sh2 component c of (X,Y,Z); c is compile-time under #pragma unroll.
__device__ __forceinline__ float sh2c(int c, float X, float Y, float Z) {
  const float s3c = 1.7320508075688772f;
  switch (c) {
    case 0: return s3c * X * Z;
    case 1: return s3c * X * Y;
    case 2: return Y * Y - 0.5f * (X * X + Z * Z);
    case 3: return s3c * Y * Z;
    default: return 0.5f * s3c * (Z * Z - X * X);
  }
}

// One fused pack: all 7 f32 matrices -> bf16 B-fragment order for 16x16x32 mfma.
__global__ void pack_all_kernel(const float* __restrict__ wr1, const float* __restrict__ wr2,
                                const float* __restrict__ l1m0, const float* __restrict__ l1m1,
                                const float* __restrict__ l2m0, const float* __restrict__ l2m1,
                                const float* __restrict__ l2m2, short* __restrict__ dst) {
  int idx = blockIdx.x * 256 + threadIdx.x;
  const float* src; int K, N, off, loc;
  if (idx < 2048)       { src = wr1;  K = 32;  N = 64;  off = OFF_WR1;  loc = idx; }
  else if (idx < 14336) { src = wr2;  K = 64;  N = 192; off = OFF_WR2;  loc = idx - 2048; }
  else if (idx < 18432) { src = l1m0; K = 64;  N = 64;  off = OFF_L1M0; loc = idx - 14336; }
  else if (idx < 34816) { src = l1m1; K = 128; N = 128; off = OFF_L1M1; loc = idx - 18432; }
  else if (idx < 38912) { src = l2m0; K = 64;  N = 64;  off = OFF_L2M0; loc = idx - 34816; }
  else if (idx < 55296) { src = l2m1; K = 128; N = 128; off = OFF_L2M1; loc = idx - 38912; }
  else if (idx < 71680) { src = l2m2; K = 128; N = 128; off = OFF_L2M2; loc = idx - 55296; }
  else return;
  int k = loc / N, c = loc - k * N;
  int n = c >> 4, f = k >> 5;
  int lane = (((k >> 3) & 3) << 4) | (c & 15);
  int jj = k & 7;
  int KF = K >> 5;
  dst[off + (((n * KF + f) << 9) + (lane << 3)) + jj] = (short)f2bf(src[loc]);
}

// Main kernel: 256 threads (4 waves) per (b,i,split); 8/ts tiles of 16 edges.
__global__ void __launch_bounds__(256, 3) so2_mfma_kernel(
    const float* __restrict__ node_vec,
    const float* __restrict__ node_tensor,
    const float* __restrict__ rbf,
    const float* __restrict__ r_hat,
    const float* __restrict__ amask,
    const float* __restrict__ b_r1,
    const float* __restrict__ b_r2,
    const short* __restrict__ wpack,
    float* __restrict__ partial,
    int ts)
{
  __shared__ __align__(16) short sUz[16 * 64];    // aliases H in phases A/B
  __shared__ __align__(16) short sUxy[16 * 128];
  __shared__ __align__(16) short sTm0[16 * 64];
  __shared__ __align__(16) short sTm1[16 * 128];
  __shared__ __align__(16) short sTm2[16 * 128];
  __shared__ __align__(16) short sGate[16 * 128]; // cols 0-63 = w1, 64-127 = w2
  __shared__ __align__(16) float sRD2[16][56];    // [c*8+v]=D2[c][v]; [40..48]=x0,y0,rx,x1,y1,ry,x2,y2,rz
  __shared__ float sMask[16];
  __shared__ float sAcc[9 * 64];

  const int bid = blockIdx.x;
  const int bi  = bid / ts;
  const int sp  = bid - bi * ts;
  const int tpb = 8 / ts;
  const int t0  = sp * tpb;
  const int tid = threadIdx.x;
  const int w   = tid >> 6;
  const int l   = tid & 63;
  const int lr  = l & 15;
  const int lg  = l >> 4;
  const int d   = l;

  for (int i = tid; i < 576; i += 256) sAcc[i] = 0.f;

  const float nv0 = node_vec[(bi * 3 + 0) * D + d];
  const float nv1 = node_vec[(bi * 3 + 1) * D + d];
  const float nv2 = node_vec[(bi * 3 + 2) * D + d];
  const float nt0 = node_tensor[(bi * 5 + 0) * D + d];
  const float nt1 = node_tensor[(bi * 5 + 1) * D + d];
  const float nt2 = node_tensor[(bi * 5 + 2) * D + d];
  const float nt3 = node_tensor[(bi * 5 + 3) * D + d];
  const float nt4 = node_tensor[(bi * 5 + 4) * D + d];

  __syncthreads();

#define LDA64(arr, kf)  (*reinterpret_cast<const short8*>(&(arr)[((lr << 6) + (kf) * 32 + (lg << 3)) ^ ((lr & 7) << 3)]))
#define LDA128(arr, kf) (*reinterpret_cast<const short8*>(&(arr)[((lr << 7) + (kf) * 32 + (lg << 3)) ^ ((lr & 7) << 3)]))
#define LDB(off, nt, KF, kf) (*reinterpret_cast<const short8*>(&wpack[(off) + (((nt) * (KF) + (kf)) << 9) + (l << 3)]))

  for (int tt = 0; tt < tpb; ++tt) {
    const int t = t0 + tt;
    const int ebase = bi * NNODE + t * 16;

    if (tid < 16) sMask[tid] = amask[ebase + tid];

    // ---- Front-end rotations FIRST: lane-parallel, edge et = 4w + (l&3);
    //      overlaps r_hat latency + Wigner VALU with phases A/B below. ----
    {
      const int et = 4 * w + (l & 3);
      const int e = ebase + et;
      const float rx = r_hat[e * 3 + 0], ry = r_hat[e * 3 + 1], rz = r_hat[e * 3 + 2];
      const bool use_x = fabsf(rz) > 0.9f;
      const float fx = use_x ? 0.f : 1.f;
      const float fz = use_x ? 1.f : 0.f;
      const float proj = fx * rx + fz * rz;
      float x0 = fx - proj * rx, x1 = -proj * ry, x2 = fz - proj * rz;
      const float invn = 1.f / (sqrtf(x0 * x0 + x1 * x1 + x2 * x2) + 1e-8f);
      x0 *= invn; x1 *= invn; x2 *= invn;
      const float y0 = ry * x2 - rz * x1;
      const float y1 = rz * x0 - rx * x2;
      const float y2 = rx * x1 - ry * x0;
      float* Rr = sRD2[et];
      if (l < 4) {
        *(float4*)&Rr[40] = make_float4(x0, y0, rx, x1);
        *(float4*)&Rr[44] = make_float4(y1, ry, x2, y2);
        Rr[48] = rz;
      }
      const float aa = 0.70710678118654752f;
      const float X1 = aa * (y0 + rx), Y1 = aa * (y1 + ry), Z1 = aa * (y2 + rz);
      const float X3 = aa * (x0 + y0), Y3 = aa * (x1 + y1), Z3 = aa * (x2 + y2);
      const float X4 = aa * (x0 + rx), Y4 = aa * (x1 + ry), Z4 = aa * (x2 + rz);
      const float tc = 0.57735026918962576f;
#pragma unroll
      for (int c = 0; c < 5; ++c) {
        const float A0 = sh2c(c, x0, x1, x2);
        const float A1 = sh2c(c, X1, Y1, Z1);
        const float A2 = sh2c(c, rx, ry, rz);
        const float A3 = sh2c(c, X3, Y3, Z3);
        const float A4 = sh2c(c, X4, Y4, Z4);
        const float d0 = tc * (2.f * A4 - A0 - A2);
        const float d1 = tc * (A2 + 2.f * A3);
        const float d2 = -(A0 + A2);
        const float d3 = tc * (A0 + 2.f * A1);
        const float d4 = tc * (A2 - A0);
        if (l < 4) {
          *(float4*)&Rr[c * 8] = make_float4(d0, d1, d2, d3);
          Rr[c * 8 + 4] = d4;
        }
      }
    }

    // ---- Phase A: H = silu(RBF @ w_r1 + b_r1) -> sUz ----
    {
      const float* rp = rbf + (size_t)(ebase + lr) * 32 + lg * 8;
      const float4 ra = *(const float4*)rp;
      const float4 rb = *(const float4*)(rp + 4);
      short8 a;
      a[0] = (short)f2bf(ra.x); a[1] = (short)f2bf(ra.y);
      a[2] = (short)f2bf(ra.z); a[3] = (short)f2bf(ra.w);
      a[4] = (short)f2bf(rb.x); a[5] = (short)f2bf(rb.y);
      a[6] = (short)f2bf(rb.z); a[7] = (short)f2bf(rb.w);
      f32x4 c = {0.f, 0.f, 0.f, 0.f};
      c = MFMA_B16(a, LDB(OFF_WR1, w, 1, 0), c);
      const int cc = w * 16 + lr;
      const float bias = b_r1[cc];
#pragma unroll
      for (int q = 0; q < 4; ++q) {
        const int rr = lg * 4 + q;
        float hv = c[q] + bias;
        hv = hv / (1.f + expf(-hv));
        sUz[((rr << 6) + cc) ^ ((rr & 7) << 3)] = (short)f2bf(hv);
      }
    }
    __syncthreads();

    // ---- Phase B: G = (H @ w_r2 + b_r2) * mask -> w0sum + gates ----
#pragma unroll
    for (int nbi = 0; nbi < 3; ++nbi) {
      const int nb = w + nbi * 4;
      f32x4 c = {0.f, 0.f, 0.f, 0.f};
#pragma unroll
      for (int kf = 0; kf < 2; ++kf)
        c = MFMA_B16(LDA64(sUz, kf), LDB(OFF_WR2, nb, 2, kf), c);
      const float bias = b_r2[nb * 16 + lr];
      if (nbi == 0) {
        float pw = 0.f;
#pragma unroll
        for (int q = 0; q < 4; ++q) { const int rr = lg * 4 + q; pw += sMask[rr] * (c[q] + bias); }
        pw += __shfl_xor(pw, 16);
        pw += __shfl_xor(pw, 32);
        if (l < 16) sAcc[w * 16 + l] += pw;
      } else {
        const int gc = (nb - 4) * 16 + lr;
#pragma unroll
        for (int q = 0; q < 4; ++q) {
          const int rr = lg * 4 + q;
          sGate[((rr << 7) + gc) ^ ((rr & 7) << 3)] = (short)f2bf((c[q] + bias) * sMask[rr]);
        }
      }
    }
    __syncthreads();

    // ---- Staging: per-edge, R/D2 from LDS broadcasts ----
#pragma unroll 1
    for (int n = 0; n < 4; ++n) {
      const int et = 4 * w + n;
      const float* Rr = sRD2[et];
      const int gb = et << 7;
      const int sw = (et & 7) << 3;
      const float a1   = bf2f((unsigned short)sGate[(gb + d) ^ sw]);
      const float a2   = bf2f((unsigned short)sGate[(gb + 64 + d) ^ sw]);
      const float a1lo = bf2f((unsigned short)sGate[(gb + (d >> 1)) ^ sw]);
      const float a1hi = bf2f((unsigned short)sGate[(gb + 32 + (d >> 1)) ^ sw]);
      const float a2lo = bf2f((unsigned short)sGate[(gb + 64 + (d >> 1)) ^ sw]);
      const float a2hi = bf2f((unsigned short)sGate[(gb + 96 + (d >> 1)) ^ sw]);
      const float vl0 = Rr[40] * nv0 + Rr[41] * nv1 + Rr[42] * nv2;
      const float vl1 = Rr[43] * nv0 + Rr[44] * nv1 + Rr[45] * nv2;
      const float vl2 = Rr[46] * nv0 + Rr[47] * nv1 + Rr[48] * nv2;
      float tl[5];
#pragma unroll
      for (int p = 0; p < 5; ++p)
        tl[p] = Rr[p * 8 + 0] * nt0 + Rr[p * 8 + 1] * nt1 + Rr[p * 8 + 2] * nt2
              + Rr[p * 8 + 3] * nt3 + Rr[p * 8 + 4] * nt4;
      const int b64 = et << 6;
      sUz [(b64 + d) ^ sw]     = (short)f2bf(vl2 * a1);
      sUxy[(gb + d) ^ sw]      = (short)f2bf(vl0 * a1lo);
      sUxy[(gb + 64 + d) ^ sw] = (short)f2bf(vl1 * a1hi);
      sTm0[(b64 + d) ^ sw]     = (short)f2bf(tl[2] * a2);
      sTm1[(gb + d) ^ sw]      = (short)f2bf(tl[1] * a2lo);
      sTm1[(gb + 64 + d) ^ sw] = (short)f2bf(tl[3] * a2hi);
      sTm2[(gb + d) ^ sw]      = (short)f2bf(tl[0] * a2lo);
      sTm2[(gb + 64 + d) ^ sw] = (short)f2bf(tl[4] * a2hi);
    }
    __syncthreads();

    // ---- Phase C: five GEMMs; wave w owns output cols [16w,16w+16) (+64 twin) ----
    {
      f32x4 z   = {0.f,0.f,0.f,0.f}, p0  = {0.f,0.f,0.f,0.f};
      f32x4 xya = {0.f,0.f,0.f,0.f}, xyb = {0.f,0.f,0.f,0.f};
      f32x4 p1a = {0.f,0.f,0.f,0.f}, p1b = {0.f,0.f,0.f,0.f};
      f32x4 p2a = {0.f,0.f,0.f,0.f}, p2b = {0.f,0.f,0.f,0.f};
#pragma unroll
      for (int kf = 0; kf < 2; ++kf) {
        z  = MFMA_B16(LDA64(sUz,  kf), LDB(OFF_L1M0, w, 2, kf), z);
        p0 = MFMA_B16(LDA64(sTm0, kf), LDB(OFF_L2M0, w, 2, kf), p0);
      }
#pragma unroll
      for (int kf = 0; kf < 4; ++kf) {
        const short8 ax = LDA128(sUxy, kf);
        xya = MFMA_B16(ax, LDB(OFF_L1M1, w,     4, kf), xya);
        xyb = MFMA_B16(ax, LDB(OFF_L1M1, w + 4, 4, kf), xyb);
        const short8 a1f = LDA128(sTm1, kf);
        p1a = MFMA_B16(a1f, LDB(OFF_L2M1, w,     4, kf), p1a);
        p1b = MFMA_B16(a1f, LDB(OFF_L2M1, w + 4, 4, kf), p1b);
        const short8 a2f = LDA128(sTm2, kf);
        p2a = MFMA_B16(a2f, LDB(OFF_L2M2, w,     4, kf), p2a);
        p2b = MFMA_B16(a2f, LDB(OFF_L2M2, w + 4, 4, kf), p2b);
      }
      float pv0 = 0.f, pv1 = 0.f, pv2 = 0.f;
      float pm[5] = {0.f, 0.f, 0.f, 0.f, 0.f};
#pragma unroll
      for (int q = 0; q < 4; ++q) {
        const int rr = lg * 4 + q;
        const float* Rr = sRD2[rr];
        const float xa = xya[q], xb = xyb[q], zz = z[q];
        pv0 += Rr[40] * xa + Rr[43] * xb + Rr[46] * zz;
        pv1 += Rr[41] * xa + Rr[44] * xb + Rr[47] * zz;
        pv2 += Rr[42] * xa + Rr[45] * xb + Rr[48] * zz;
        const float m2a = p2a[q], m1a = p1a[q], m0 = p0[q], m1b = p1b[q], m2b = p2b[q];
#pragma unroll
        for (int p = 0; p < 5; ++p)
          pm[p] += Rr[0 * 8 + p] * m2a + Rr[1 * 8 + p] * m1a + Rr[2 * 8 + p] * m0
                 + Rr[3 * 8 + p] * m1b + Rr[4 * 8 + p] * m2b;
      }
      pv0 += __shfl_xor(pv0, 16); pv0 += __shfl_xor(pv0, 32);
      pv1 += __shfl_xor(pv1, 16); pv1 += __shfl_xor(pv1, 32);
      pv2 += __shfl_xor(pv2, 16); pv2 += __shfl_xor(pv2, 32);
#pragma unroll
      for (int p = 0; p < 5; ++p) { pm[p] += __shfl_xor(pm[p], 16); pm[p] += __shfl_xor(pm[p], 32); }
      if (l < 16) {
        const int cc = w * 16 + l;
        sAcc[1 * 64 + cc] += pv0;
        sAcc[2 * 64 + cc] += pv1;
        sAcc[3 * 64 + cc] += pv2;
#pragma unroll
        for (int p = 0; p < 5; ++p) sAcc[(4 + p) * 64 + cc] += pm[p];
      }
    }
    __syncthreads();
  }

  for (int i = tid; i < 576; i += 256) partial[(size_t)bid * 576 + i] = sAcc[i];
#undef LDA64
#undef LDA128
#undef LDB
}

// Kernel 2: reduce partials, scalar epilogue, LayerNorm — 4-wave parallel.
__global__ void __launch_bounds__(256) so2_epilogue_kernel(
    const float* __restrict__ node_scalar,
    const float* __restrict__ w_l0,
    const float* __restrict__ w_out,
    const float* __restrict__ b_out,
    const float* __restrict__ g_s,
    const float* __restrict__ beta_s,
    const float* __restrict__ g_v,
    const float* __restrict__ beta_v,
    const float* __restrict__ g_t,
    const float* __restrict__ beta_t,
    const float* __restrict__ pws,
    int jsplit,
    float* __restrict__ out)
{
  __shared__ float sf[9 * D];
  __shared__ float sns[D];
  __shared__ float stmp[D];

  const int bi = blockIdx.x;
  const int tid = threadIdx.x;
  const int w = tid >> 6;
  const int l = tid & 63;

  for (int idx = tid; idx < 9 * D; idx += 256) {
    float s = 0.f;
    for (int sp = 0; sp < jsplit; ++sp)
      s += pws[(size_t)(bi * jsplit + sp) * (9 * D) + idx];
    sf[idx] = s;
  }
  if (tid < D) sns[tid] = node_scalar[bi * D + tid];
  __syncthreads();

  const int c  = w * 16 + (l & 15);   // output column for matvec phases
  const int k0 = (l >> 4) * 16;       // k-chunk for this lane group

  // ---- matvec1: s0 = (node_scalar @ w_l0)[c];  stmp[c] = s0 * w0sum[c] ----
  {
    float s = 0.f;
#pragma unroll
    for (int k = 0; k < 16; ++k) s = fmaf(sns[k0 + k], w_l0[(k0 + k) * D + c], s);
    s += __shfl_xor(s, 16);
    s += __shfl_xor(s, 32);
    if (l < 16) stmp[c] = s * sf[c];
  }
  __syncthreads();

  // ---- matvec2: pre[c] = b_out[c] + (stmp @ w_out)[c]; overwrite sf row 0 ----
  {
    float s = 0.f;
#pragma unroll
    for (int k = 0; k < 16; ++k) s = fmaf(stmp[k0 + k], w_out[(k0 + k) * D + c], s);
    s += __shfl_xor(s, 16);
    s += __shfl_xor(s, 32);
    if (l < 16) sf[c] = s + b_out[c];
  }
  __syncthreads();

  // ---- LayerNorm: rows distributed across waves (w, w+4, w+8) ----
  for (int r = w; r < 9; r += 4) {
    const float x = sf[r * D + l];
    float s = x;
#pragma unroll
    for (int off = 32; off > 0; off >>= 1) s += __shfl_xor(s, off, 64);
    const float mu = s * (1.f / 64.f);
    const float xm = x - mu;
    float v = xm * xm;
#pragma unroll
    for (int off = 32; off > 0; off >>= 1) v += __shfl_xor(v, off, 64);
    const float var = v * (1.f / 64.f);
    const float rstd = rsqrtf(var + 1e-5f);
    float g, be;
    int off_out;
    if (r == 0)      { g = g_s[l]; be = beta_s[l]; off_out = bi * D + l; }
    else if (r < 4)  { g = g_v[l]; be = beta_v[l]; off_out = 16384 + (bi * 3 + (r - 1)) * D + l; }
    else             { g = g_t[l]; be = beta_t[l]; off_out = 65536 + (bi * 5 + (r - 4)) * D + l; }
    out[off_out] = xm * rstd * g + be;
  }
}

extern "C" void kernel_launch(void* const* d_in, const int* in_sizes, int n_in,
                              void* d_out, int out_size, void* d_ws, size_t ws_size,
                              hipStream_t stream) {
  const float* p[24];
  for (int i = 0; i < 24; ++i) p[i] = (const float*)d_in[i];
  short* wpack = (short*)d_ws;
  float* partial = (float*)((char*)d_ws + PART_OFF);

  int ts = 8;
  while (ts > 1 && ws_size < (size_t)PART_OFF + (size_t)256 * ts * 576 * sizeof(float))
    ts >>= 1;

  pack_all_kernel<<<dim3(280), dim3(256), 0, stream>>>(
      p[6], p[8], p[11], p[12], p[13], p[14], p[15], wpack);

  so2_mfma_kernel<<<dim3(256 * ts), dim3(256), 0, stream>>>(
      p[1], p[2], p[3], p[4], p[5], p[7], p[9], wpack, partial, ts);

  so2_epilogue_kernel<<<dim3(256), dim3(256), 0, stream>>>(
      p[0], p[10], p[16], p[17], p[18], p[19], p[20], p[21], p[22], p[23],
      partial, ts, (float*)d_out);
}

// Round 15
// 62.518 us; speedup vs baseline: 1.5228x; 1.5228x over previous
//
#include <hip/hip_runtime.h>
#include <hip/hip_bf16.h>
#include <math.h>

#define D 64
#define NNODE 128

typedef __attribute__((ext_vector_type(8))) short short8;
typedef __attribute__((ext_vector_type(4))) float f32x4;

#define MFMA_B16(a,b,c) __builtin_amdgcn_mfma_f32_16x16x32_bf16((a),(b),(c),0,0,0)

// weight pack offsets (in shorts): layout [ntile][kfrag][lane(64)][jj(8)]
#define OFF_WR1   0        // 32x64  : KF=1, NT=4   -> 2048
#define OFF_WR2   2048     // 64x192 : KF=2, NT=12  -> 12288
#define OFF_L1M0  14336    // 64x64  : KF=2, NT=4   -> 4096
#define OFF_L1M1  18432    // 128x128: KF=4, NT=8   -> 16384
#define OFF_L2M0  34816
#define OFF_L2M1  38912
#define OFF_L2M2  55296
#define PACK_SHORTS 71680
#define PART_OFF  147456   // bytes; partials (f32) start here in d_ws

__device__ __forceinline__ unsigned short f2bf(float f) {
  unsigned int u = __float_as_uint(f);
  u += 0x7FFFu + ((u >> 16) & 1u);
  return (unsigned short)(u >> 16);
}
__device__ __forceinline__ float bf2f(unsigned short s) {
  return __uint_as_float(((unsigned int)s) << 16);
}

// sh2 component c of (X,Y,Z); c is compile-time under #pragma unroll.
__device__ __forceinline__ float sh2c(int c, float X, float Y, float Z) {
  const float s3c = 1.7320508075688772f;
  switch (c) {
    case 0: return s3c * X * Z;
    case 1: return s3c * X * Y;
    case 2: return Y * Y - 0.5f * (X * X + Z * Z);
    case 3: return s3c * Y * Z;
    default: return 0.5f * s3c * (Z * Z - X * X);
  }
}

// One fused pack: all 7 f32 matrices -> bf16 B-fragment order for 16x16x32 mfma.
__global__ void pack_all_kernel(const float* __restrict__ wr1, const float* __restrict__ wr2,
                                const float* __restrict__ l1m0, const float* __restrict__ l1m1,
                                const float* __restrict__ l2m0, const float* __restrict__ l2m1,
                                const float* __restrict__ l2m2, short* __restrict__ dst) {
  int idx = blockIdx.x * 256 + threadIdx.x;
  const float* src; int K, N, off, loc;
  if (idx < 2048)       { src = wr1;  K = 32;  N = 64;  off = OFF_WR1;  loc = idx; }
  else if (idx < 14336) { src = wr2;  K = 64;  N = 192; off = OFF_WR2;  loc = idx - 2048; }
  else if (idx < 18432) { src = l1m0; K = 64;  N = 64;  off = OFF_L1M0; loc = idx - 14336; }
  else if (idx < 34816) { src = l1m1; K = 128; N = 128; off = OFF_L1M1; loc = idx - 18432; }
  else if (idx < 38912) { src = l2m0; K = 64;  N = 64;  off = OFF_L2M0; loc = idx - 34816; }
  else if (idx < 55296) { src = l2m1; K = 128; N = 128; off = OFF_L2M1; loc = idx - 38912; }
  else if (idx < 71680) { src = l2m2; K = 128; N = 128; off = OFF_L2M2; loc = idx - 55296; }
  else return;
  int k = loc / N, c = loc - k * N;
  int n = c >> 4, f = k >> 5;
  int lane = (((k >> 3) & 3) << 4) | (c & 15);
  int jj = k & 7;
  int KF = K >> 5;
  dst[off + (((n * KF + f) << 9) + (lane << 3)) + jj] = (short)f2bf(src[loc]);
}

// Main kernel (round-13 structure): 256 threads (4 waves) per (b,i,split).
__global__ void __launch_bounds__(256, 3) so2_mfma_kernel(
    const float* __restrict__ node_vec,
    const float* __restrict__ node_tensor,
    const float* __restrict__ rbf,
    const float* __restrict__ r_hat,
    const float* __restrict__ amask,
    const float* __restrict__ b_r1,
    const float* __restrict__ b_r2,
    const short* __restrict__ wpack,
    float* __restrict__ partial,
    int ts)
{
  __shared__ __align__(16) short sUz[16 * 64];    // aliases H in phases A/B
  __shared__ __align__(16) short sUxy[16 * 128];
  __shared__ __align__(16) short sTm0[16 * 64];
  __shared__ __align__(16) short sTm1[16 * 128];
  __shared__ __align__(16) short sTm2[16 * 128];
  __shared__ __align__(16) short sGate[16 * 128]; // cols 0-63 = w1, 64-127 = w2
  __shared__ __align__(16) float sRD2[16][56];    // [c*8+v]=D2[c][v]; [40..48]=x0,y0,rx,x1,y1,ry,x2,y2,rz
  __shared__ float sMask[16];
  __shared__ float sAcc[9 * 64];

  const int bid = blockIdx.x;
  const int bi  = bid / ts;
  const int sp  = bid - bi * ts;
  const int tpb = 8 / ts;
  const int t0  = sp * tpb;
  const int tid = threadIdx.x;
  const int w   = tid >> 6;
  const int l   = tid & 63;
  const int lr  = l & 15;
  const int lg  = l >> 4;
  const int d   = l;

  for (int i = tid; i < 576; i += 256) sAcc[i] = 0.f;

  const float nv0 = node_vec[(bi * 3 + 0) * D + d];
  const float nv1 = node_vec[(bi * 3 + 1) * D + d];
  const float nv2 = node_vec[(bi * 3 + 2) * D + d];
  const float nt0 = node_tensor[(bi * 5 + 0) * D + d];
  const float nt1 = node_tensor[(bi * 5 + 1) * D + d];
  const float nt2 = node_tensor[(bi * 5 + 2) * D + d];
  const float nt3 = node_tensor[(bi * 5 + 3) * D + d];
  const float nt4 = node_tensor[(bi * 5 + 4) * D + d];

  __syncthreads();

#define LDA64(arr, kf)  (*reinterpret_cast<const short8*>(&(arr)[((lr << 6) + (kf) * 32 + (lg << 3)) ^ ((lr & 7) << 3)]))
#define LDA128(arr, kf) (*reinterpret_cast<const short8*>(&(arr)[((lr << 7) + (kf) * 32 + (lg << 3)) ^ ((lr & 7) << 3)]))
#define LDB(off, nt, KF, kf) (*reinterpret_cast<const short8*>(&wpack[(off) + (((nt) * (KF) + (kf)) << 9) + (l << 3)]))

  for (int tt = 0; tt < tpb; ++tt) {
    const int t = t0 + tt;
    const int ebase = bi * NNODE + t * 16;

    if (tid < 16) sMask[tid] = amask[ebase + tid];

    // ---- Phase A: H = silu(RBF @ w_r1 + b_r1) -> sUz ----
    {
      const float* rp = rbf + (size_t)(ebase + lr) * 32 + lg * 8;
      const float4 ra = *(const float4*)rp;
      const float4 rb = *(const float4*)(rp + 4);
      short8 a;
      a[0] = (short)f2bf(ra.x); a[1] = (short)f2bf(ra.y);
      a[2] = (short)f2bf(ra.z); a[3] = (short)f2bf(ra.w);
      a[4] = (short)f2bf(rb.x); a[5] = (short)f2bf(rb.y);
      a[6] = (short)f2bf(rb.z); a[7] = (short)f2bf(rb.w);
      f32x4 c = {0.f, 0.f, 0.f, 0.f};
      c = MFMA_B16(a, LDB(OFF_WR1, w, 1, 0), c);
      const int cc = w * 16 + lr;
      const float bias = b_r1[cc];
#pragma unroll
      for (int q = 0; q < 4; ++q) {
        const int rr = lg * 4 + q;
        float hv = c[q] + bias;
        hv = hv / (1.f + expf(-hv));
        sUz[((rr << 6) + cc) ^ ((rr & 7) << 3)] = (short)f2bf(hv);
      }
    }
    __syncthreads();

    // ---- Phase B: G = (H @ w_r2 + b_r2) * mask -> w0sum + gates ----
#pragma unroll
    for (int nbi = 0; nbi < 3; ++nbi) {
      const int nb = w + nbi * 4;
      f32x4 c = {0.f, 0.f, 0.f, 0.f};
#pragma unroll
      for (int kf = 0; kf < 2; ++kf)
        c = MFMA_B16(LDA64(sUz, kf), LDB(OFF_WR2, nb, 2, kf), c);
      const float bias = b_r2[nb * 16 + lr];
      if (nbi == 0) {
        float pw = 0.f;
#pragma unroll
        for (int q = 0; q < 4; ++q) { const int rr = lg * 4 + q; pw += sMask[rr] * (c[q] + bias); }
        pw += __shfl_xor(pw, 16);
        pw += __shfl_xor(pw, 32);
        if (l < 16) sAcc[w * 16 + l] += pw;
      } else {
        const int gc = (nb - 4) * 16 + lr;
#pragma unroll
        for (int q = 0; q < 4; ++q) {
          const int rr = lg * 4 + q;
          sGate[((rr << 7) + gc) ^ ((rr & 7) << 3)] = (short)f2bf((c[q] + bias) * sMask[rr]);
        }
      }
    }
    __syncthreads();

    // ---- Front-end rotations: lane-parallel, edge et = 4w + (l&3); D2 rows
    //      streamed to LDS one at a time to cap register pressure ----
    {
      const int et = 4 * w + (l & 3);
      const int e = ebase + et;
      const float rx = r_hat[e * 3 + 0], ry = r_hat[e * 3 + 1], rz = r_hat[e * 3 + 2];
      const bool use_x = fabsf(rz) > 0.9f;
      const float fx = use_x ? 0.f : 1.f;
      const float fz = use_x ? 1.f : 0.f;
      const float proj = fx * rx + fz * rz;
      float x0 = fx - proj * rx, x1 = -proj * ry, x2 = fz - proj * rz;
      const float invn = 1.f / (sqrtf(x0 * x0 + x1 * x1 + x2 * x2) + 1e-8f);
      x0 *= invn; x1 *= invn; x2 *= invn;
      const float y0 = ry * x2 - rz * x1;
      const float y1 = rz * x0 - rx * x2;
      const float y2 = rx * x1 - ry * x0;
      float* Rr = sRD2[et];
      if (l < 4) {
        *(float4*)&Rr[40] = make_float4(x0, y0, rx, x1);
        *(float4*)&Rr[44] = make_float4(y1, ry, x2, y2);
        Rr[48] = rz;
      }
      const float aa = 0.70710678118654752f;
      const float X1 = aa * (y0 + rx), Y1 = aa * (y1 + ry), Z1 = aa * (y2 + rz);
      const float X3 = aa * (x0 + y0), Y3 = aa * (x1 + y1), Z3 = aa * (x2 + y2);
      const float X4 = aa * (x0 + rx), Y4 = aa * (x1 + ry), Z4 = aa * (x2 + rz);
      const float tc = 0.57735026918962576f;
#pragma unroll
      for (int c = 0; c < 5; ++c) {
        const float A0 = sh2c(c, x0, x1, x2);
        const float A1 = sh2c(c, X1, Y1, Z1);
        const float A2 = sh2c(c, rx, ry, rz);
        const float A3 = sh2c(c, X3, Y3, Z3);
        const float A4 = sh2c(c, X4, Y4, Z4);
        const float d0 = tc * (2.f * A4 - A0 - A2);
        const float d1 = tc * (A2 + 2.f * A3);
        const float d2 = -(A0 + A2);
        const float d3 = tc * (A0 + 2.f * A1);
        const float d4 = tc * (A2 - A0);
        if (l < 4) {
          *(float4*)&Rr[c * 8] = make_float4(d0, d1, d2, d3);
          Rr[c * 8 + 4] = d4;
        }
      }
    }
    asm volatile("s_waitcnt lgkmcnt(0)" ::: "memory");   // intra-wave: sRD2 rows 4w..4w+3 visible

    // ---- Staging: per-edge, R/D2 from LDS broadcasts ----
#pragma unroll 1
    for (int n = 0; n < 4; ++n) {
      const int et = 4 * w + n;
      const float* Rr = sRD2[et];
      const int gb = et << 7;
      const int sw = (et & 7) << 3;
      const float a1   = bf2f((unsigned short)sGate[(gb + d) ^ sw]);
      const float a2   = bf2f((unsigned short)sGate[(gb + 64 + d) ^ sw]);
      const float a1lo = bf2f((unsigned short)sGate[(gb + (d >> 1)) ^ sw]);
      const float a1hi = bf2f((unsigned short)sGate[(gb + 32 + (d >> 1)) ^ sw]);
      const float a2lo = bf2f((unsigned short)sGate[(gb + 64 + (d >> 1)) ^ sw]);
      const float a2hi = bf2f((unsigned short)sGate[(gb + 96 + (d >> 1)) ^ sw]);
      const float vl0 = Rr[40] * nv0 + Rr[41] * nv1 + Rr[42] * nv2;
      const float vl1 = Rr[43] * nv0 + Rr[44] * nv1 + Rr[45] * nv2;
      const float vl2 = Rr[46] * nv0 + Rr[47] * nv1 + Rr[48] * nv2;
      float tl[5];
#pragma unroll
      for (int p = 0; p < 5; ++p)
        tl[p] = Rr[p * 8 + 0] * nt0 + Rr[p * 8 + 1] * nt1 + Rr[p * 8 + 2] * nt2
              + Rr[p * 8 + 3] * nt3 + Rr[p * 8 + 4] * nt4;
      const int b64 = et << 6;
      sUz [(b64 + d) ^ sw]     = (short)f2bf(vl2 * a1);
      sUxy[(gb + d) ^ sw]      = (short)f2bf(vl0 * a1lo);
      sUxy[(gb + 64 + d) ^ sw] = (short)f2bf(vl1 * a1hi);
      sTm0[(b64 + d) ^ sw]     = (short)f2bf(tl[2] * a2);
      sTm1[(gb + d) ^ sw]      = (short)f2bf(tl[1] * a2lo);
      sTm1[(gb + 64 + d) ^ sw] = (short)f2bf(tl[3] * a2hi);
      sTm2[(gb + d) ^ sw]      = (short)f2bf(tl[0] * a2lo);
      sTm2[(gb + 64 + d) ^ sw] = (short)f2bf(tl[4] * a2hi);
    }
    __syncthreads();

    // ---- Phase C: five GEMMs; wave w owns output cols [16w,16w+16) (+64 twin) ----
    {
      f32x4 z   = {0.f,0.f,0.f,0.f}, p0  = {0.f,0.f,0.f,0.f};
      f32x4 xya = {0.f,0.f,0.f,0.f}, xyb = {0.f,0.f,0.f,0.f};
      f32x4 p1a = {0.f,0.f,0.f,0.f}, p1b = {0.f,0.f,0.f,0.f};
      f32x4 p2a = {0.f,0.f,0.f,0.f}, p2b = {0.f,0.f,0.f,0.f};
#pragma unroll
      for (int kf = 0; kf < 2; ++kf) {
        z  = MFMA_B16(LDA64(sUz,  kf), LDB(OFF_L1M0, w, 2, kf), z);
        p0 = MFMA_B16(LDA64(sTm0, kf), LDB(OFF_L2M0, w, 2, kf), p0);
      }
#pragma unroll
      for (int kf = 0; kf < 4; ++kf) {
        const short8 ax = LDA128(sUxy, kf);
        xya = MFMA_B16(ax, LDB(OFF_L1M1, w,     4, kf), xya);
        xyb = MFMA_B16(ax, LDB(OFF_L1M1, w + 4, 4, kf), xyb);
        const short8 a1f = LDA128(sTm1, kf);
        p1a = MFMA_B16(a1f, LDB(OFF_L2M1, w,     4, kf), p1a);
        p1b = MFMA_B16(a1f, LDB(OFF_L2M1, w + 4, 4, kf), p1b);
        const short8 a2f = LDA128(sTm2, kf);
        p2a = MFMA_B16(a2f, LDB(OFF_L2M2, w,     4, kf), p2a);
        p2b = MFMA_B16(a2f, LDB(OFF_L2M2, w + 4, 4, kf), p2b);
      }
      float pv0 = 0.f, pv1 = 0.f, pv2 = 0.f;
      float pm[5] = {0.f, 0.f, 0.f, 0.f, 0.f};
#pragma unroll
      for (int q = 0; q < 4; ++q) {
        const int rr = lg * 4 + q;
        const float* Rr = sRD2[rr];
        const float xa = xya[q], xb = xyb[q], zz = z[q];
        pv0 += Rr[40] * xa + Rr[43] * xb + Rr[46] * zz;
        pv1 += Rr[41] * xa + Rr[44] * xb + Rr[47] * zz;
        pv2 += Rr[42] * xa + Rr[45] * xb + Rr[48] * zz;
        const float m2a = p2a[q], m1a = p1a[q], m0 = p0[q], m1b = p1b[q], m2b = p2b[q];
#pragma unroll
        for (int p = 0; p < 5; ++p)
          pm[p] += Rr[0 * 8 + p] * m2a + Rr[1 * 8 + p] * m1a + Rr[2 * 8 + p] * m0
                 + Rr[3 * 8 + p] * m1b + Rr[4 * 8 + p] * m2b;
      }
      pv0 += __shfl_xor(pv0, 16); pv0 += __shfl_xor(pv0, 32);
      pv1 += __shfl_xor(pv1, 16); pv1 += __shfl_xor(pv1, 32);
      pv2 += __shfl_xor(pv2, 16); pv2 += __shfl_xor(pv2, 32);
#pragma unroll
      for (int p = 0; p < 5; ++p) { pm[p] += __shfl_xor(pm[p], 16); pm[p] += __shfl_xor(pm[p], 32); }
      if (l < 16) {
        const int cc = w * 16 + l;
        sAcc[1 * 64 + cc] += pv0;
        sAcc[2 * 64 + cc] += pv1;
        sAcc[3 * 64 + cc] += pv2;
#pragma unroll
        for (int p = 0; p < 5; ++p) sAcc[(4 + p) * 64 + cc] += pm[p];
      }
    }
    __syncthreads();
  }

  for (int i = tid; i < 576; i += 256) partial[(size_t)bid * 576 + i] = sAcc[i];
#undef LDA64
#undef LDA128
#undef LDB
}

// Kernel 2: reduce partials, scalar epilogue, LayerNorm — 4-wave parallel.
__global__ void __launch_bounds__(256) so2_epilogue_kernel(
    const float* __restrict__ node_scalar,
    const float* __restrict__ w_l0,
    const float* __restrict__ w_out,
    const float* __restrict__ b_out,
    const float* __restrict__ g_s,
    const float* __restrict__ beta_s,
    const float* __restrict__ g_v,
    const float* __restrict__ beta_v,
    const float* __restrict__ g_t,
    const float* __restrict__ beta_t,
    const float* __restrict__ pws,
    int jsplit,
    float* __restrict__ out)
{
  __shared__ float sf[9 * D];
  __shared__ float sns[D];
  __shared__ float stmp[D];

  const int bi = blockIdx.x;
  const int tid = threadIdx.x;
  const int w = tid >> 6;
  const int l = tid & 63;

  for (int idx = tid; idx < 9 * D; idx += 256) {
    float s = 0.f;
    for (int sp = 0; sp < jsplit; ++sp)
      s += pws[(size_t)(bi * jsplit + sp) * (9 * D) + idx];
    sf[idx] = s;
  }
  if (tid < D) sns[tid] = node_scalar[bi * D + tid];
  __syncthreads();

  const int c  = w * 16 + (l & 15);   // output column for matvec phases
  const int k0 = (l >> 4) * 16;       // k-chunk for this lane group

  // ---- matvec1: s0 = (node_scalar @ w_l0)[c];  stmp[c] = s0 * w0sum[c] ----
  {
    float s = 0.f;
#pragma unroll
    for (int k = 0; k < 16; ++k) s = fmaf(sns[k0 + k], w_l0[(k0 + k) * D + c], s);
    s += __shfl_xor(s, 16);
    s += __shfl_xor(s, 32);
    if (l < 16) stmp[c] = s * sf[c];
  }
  __syncthreads();

  // ---- matvec2: pre[c] = b_out[c] + (stmp @ w_out)[c]; overwrite sf row 0 ----
  {
    float s = 0.f;
#pragma unroll
    for (int k = 0; k < 16; ++k) s = fmaf(stmp[k0 + k], w_out[(k0 + k) * D + c], s);
    s += __shfl_xor(s, 16);
    s += __shfl_xor(s, 32);
    if (l < 16) sf[c] = s + b_out[c];
  }
  __syncthreads();

  // ---- LayerNorm: rows distributed across waves (w, w+4, w+8) ----
  for (int r = w; r < 9; r += 4) {
    const float x = sf[r * D + l];
    float s = x;
#pragma unroll
    for (int off = 32; off > 0; off >>= 1) s += __shfl_xor(s, off, 64);
    const float mu = s * (1.f / 64.f);
    const float xm = x - mu;
    float v = xm * xm;
#pragma unroll
    for (int off = 32; off > 0; off >>= 1) v += __shfl_xor(v, off, 64);
    const float var = v * (1.f / 64.f);
    const float rstd = rsqrtf(var + 1e-5f);
    float g, be;
    int off_out;
    if (r == 0)      { g = g_s[l]; be = beta_s[l]; off_out = bi * D + l; }
    else if (r < 4)  { g = g_v[l]; be = beta_v[l]; off_out = 16384 + (bi * 3 + (r - 1)) * D + l; }
    else             { g = g_t[l]; be = beta_t[l]; off_out = 65536 + (bi * 5 + (r - 4)) * D + l; }
    out[off_out] = xm * rstd * g + be;
  }
}

extern "C" void kernel_launch(void* const* d_in, const int* in_sizes, int n_in,
                              void* d_out, int out_size, void* d_ws, size_t ws_size,
                              hipStream_t stream) {
  const float* p[24];
  for (int i = 0; i < 24; ++i) p[i] = (const float*)d_in[i];
  short* wpack = (short*)d_ws;
  float* partial = (float*)((char*)d_ws + PART_OFF);

  int ts = 8;
  while (ts > 1 && ws_size < (size_t)PART_OFF + (size_t)256 * ts * 576 * sizeof(float))
    ts >>= 1;

  pack_all_kernel<<<dim3(280), dim3(256), 0, stream>>>(
      p[6], p[8], p[11], p[12], p[13], p[14], p[15], wpack);

  so2_mfma_kernel<<<dim3(256 * ts), dim3(256), 0, stream>>>(
      p[1], p[2], p[3], p[4], p[5], p[7], p[9], wpack, partial, ts);

  so2_epilogue_kernel<<<dim3(256), dim3(256), 0, stream>>>(
      p[0], p[10], p[16], p[17], p[18], p[19], p[20], p[21], p[22], p[23],
      partial, ts, (float*)d_out);
}